// Round 15
// baseline (164.890 us; speedup 1.0000x reference)
//
#include <hip/hip_runtime.h>
#include <hip/hip_bf16.h>

typedef __attribute__((ext_vector_type(4))) float  f32x4;
typedef __attribute__((ext_vector_type(8))) short  short8;
typedef unsigned int u32;

#define EMBED 4096
#define LR    512
#define KSEL  128
#define BATCH 8192

__device__ __forceinline__ short f2bf(float x) {
  union { float f; unsigned u; } c; c.f = x;
  unsigned r = c.u + 0x7FFFu + ((c.u >> 16) & 1u);  // RNE
  return (short)(r >> 16);
}
__device__ __forceinline__ void gload16(const void* g, void* l) {
  __builtin_amdgcn_global_load_lds((const __attribute__((address_space(1))) u32*)g,
                                   (__attribute__((address_space(3))) u32*)l, 16, 0, 0);
}
// Streaming store: nt + sc1 = non-temporal / no-allocate at MALL (L3).
// __builtin_nontemporal_store emits only `nt`, which R12 showed does NOT
// stop L3 write-allocation (FETCH unchanged). This is the sc1 variant.
__device__ __forceinline__ void store_stream(float* p, float v) {
  asm volatile("global_store_dword %0, %1, off nt sc1"
               :: "v"(p), "v"(v) : "memory");
}

// K0: gather selected columns of W, emit two bf16 MFMA-packed layouts.
// Wp : [e/8][128 cols][8]  (B-operand for GEMM1: kk-dim = embed)
// Wtp: [c/8][4096 e ][8]  (B-operand for GEMM2: kk-dim = sel index)
__global__ __launch_bounds__(256) void pack_w_kernel(
    const float* __restrict__ W, const int* __restrict__ sel,
    short* __restrict__ Wp, short* __restrict__ Wtp) {
  int idx = blockIdx.x * 256 + threadIdx.x;
  int e = idx >> 7;
  int c = idx & 127;
  int r = sel[c];
  short v = f2bf(W[e * LR + r]);
  Wp [(((e >> 3) << 7) + c) * 8 + (e & 7)] = v;
  Wtp[(((c >> 3) << 12) + e) * 8 + (c & 7)] = v;
}

// K1: Tp (packed bf16 [kk/8][8192][8]) = (src - base) @ Wsel
// R8/R12 champion structure, unchanged. The round-15 change is gemm2's
// store policy (nt sc1). If MALL write-bypass works, this kernel's
// steady-state FETCH_SIZE collapses 138 MB -> <30 MB and its duration
// falls toward the L3-read bound.
__global__ __launch_bounds__(256, 2) void gemm1_kernel(
    const float* __restrict__ base, const float* __restrict__ src,
    const short* __restrict__ Wp, short* __restrict__ Tp) {
  __shared__ __align__(16) char smem[65536];   // 2 bufs x (16 rows x 1KB x 2 arr)
  const int t  = threadIdx.x;
  const int w  = t >> 6, l = t & 63;
  const int lr = l & 15, lg = l >> 4;
  const int row0 = blockIdx.x * 16;
  const int srow = t >> 6;       // base row (0..3), +4 per issue
  const int sc   = t & 63;       // 16B chunk within a 1KB row-slice

  #define STAGE(s, b) do {                                                  \
    char* d_ = smem + (b) * 32768 + t * 16;                                 \
    _Pragma("unroll")                                                       \
    for (int i = 0; i < 4; ++i) {                                           \
      const int row = i * 4 + srow;                                         \
      const size_t go = (size_t)(row0 + row) * EMBED + (s) * 256            \
                        + ((sc ^ (row & 7)) << 2);                          \
      gload16(base + go, d_ + i * 4096);                                    \
      gload16(src  + go, d_ + 16384 + i * 4096);                            \
    }                                                                       \
  } while (0)

  const short8* wq = (const short8*)Wp;
  f32x4 acc0 = {0.f, 0.f, 0.f, 0.f}, acc1 = {0.f, 0.f, 0.f, 0.f};

  STAGE(0, 0);
  int b = 0;
  for (int s = 0; s < 16; ++s) {
    __syncthreads();                         // buf b staged
    const int kc = s * 256;
    short8 bf[16];                           // B-frags first (older in queue)
    #pragma unroll
    for (int kstep = 0; kstep < 8; ++kstep) {
      const int kg = ((kc + kstep * 32) >> 3) + lg;
      bf[kstep * 2]     = wq[(size_t)kg * 128 + w * 32 + lr];
      bf[kstep * 2 + 1] = wq[(size_t)kg * 128 + w * 32 + 16 + lr];
    }
    if (s < 15) STAGE(s + 1, b ^ 1);         // flies under this step's compute
    const char* tb = smem + b * 32768 + lr * 1024;
    #pragma unroll
    for (int kstep = 0; kstep < 8; ++kstep) {
      const int j0 = (kstep * 8 + lg * 2)     ^ (lr & 7);
      const int j1 = (kstep * 8 + lg * 2 + 1) ^ (lr & 7);
      f32x4 b0 = *(const f32x4*)(tb + j0 * 16);
      f32x4 b1 = *(const f32x4*)(tb + j1 * 16);
      f32x4 s0 = *(const f32x4*)(tb + 16384 + j0 * 16);
      f32x4 s1 = *(const f32x4*)(tb + 16384 + j1 * 16);
      union { short8 v; __hip_bfloat162 h[4]; } u;
      u.h[0] = __float22bfloat162_rn(make_float2(s0[0] - b0[0], s0[1] - b0[1]));
      u.h[1] = __float22bfloat162_rn(make_float2(s0[2] - b0[2], s0[3] - b0[3]));
      u.h[2] = __float22bfloat162_rn(make_float2(s1[0] - b1[0], s1[1] - b1[1]));
      u.h[3] = __float22bfloat162_rn(make_float2(s1[2] - b1[2], s1[3] - b1[3]));
      acc0 = __builtin_amdgcn_mfma_f32_16x16x32_bf16(u.v, bf[kstep * 2],     acc0, 0, 0, 0);
      acc1 = __builtin_amdgcn_mfma_f32_16x16x32_bf16(u.v, bf[kstep * 2 + 1], acc1, 0, 0, 0);
    }
    b ^= 1;
  }
  #undef STAGE

  // lane holds T[row0 + 4lg + r][kk = w*32 + ct*16 + lr]
  #pragma unroll
  for (int ct = 0; ct < 2; ++ct) {
    f32x4 a = ct ? acc1 : acc0;
    const int kk = w * 32 + ct * 16 + lr;
    short* dst = Tp + (size_t)(((kk >> 3) << 13) + row0 + (lg << 2)) * 8 + (kk & 7);
    #pragma unroll
    for (int r = 0; r < 4; ++r) dst[r * 8] = f2bf(a[r]);
  }
}

// K2: out = base + T @ Wsel^T. Block: 64 rows x 256 cols, 4 waves.
// out-stores: nt sc1 streaming (no MALL allocation).
__global__ __launch_bounds__(256) void gemm2_kernel(
    const float* __restrict__ base, const short* __restrict__ Tp,
    const short* __restrict__ Wtp, float* __restrict__ out) {
  const int t  = threadIdx.x;
  const int w  = t >> 6, l = t & 63;
  const int lr = l & 15, lg = l >> 4;
  const int mt = blockIdx.x >> 4, nt = blockIdx.x & 15;
  const int row0 = mt * 64;
  const int col0 = nt * 256 + w * 64;

  short8 afr[4][4];
  #pragma unroll
  for (int m = 0; m < 4; ++m)
    #pragma unroll
    for (int ks = 0; ks < 4; ++ks)
      afr[m][ks] = *(const short8*)(Tp + (size_t)(((ks * 4 + lg) << 13) + row0 + m * 16 + lr) * 8);

  f32x4 acc[4][4];
  #pragma unroll
  for (int m = 0; m < 4; ++m)
    #pragma unroll
    for (int nf = 0; nf < 4; ++nf) acc[m][nf] = (f32x4){0.f, 0.f, 0.f, 0.f};

  #pragma unroll
  for (int nf = 0; nf < 4; ++nf) {
    short8 bfr[4];
    #pragma unroll
    for (int ks = 0; ks < 4; ++ks)
      bfr[ks] = *(const short8*)(Wtp + (size_t)(((ks * 4 + lg) << 12) + col0 + nf * 16 + lr) * 8);
    #pragma unroll
    for (int m = 0; m < 4; ++m)
      #pragma unroll
      for (int ks = 0; ks < 4; ++ks)
        acc[m][nf] = __builtin_amdgcn_mfma_f32_16x16x32_bf16(afr[m][ks], bfr[ks], acc[m][nf], 0, 0, 0);
  }

  #pragma unroll
  for (int m = 0; m < 4; ++m)
    #pragma unroll
    for (int r = 0; r < 4; ++r) {
      const size_t row = row0 + m * 16 + lg * 4 + r;
      #pragma unroll
      for (int nf = 0; nf < 4; ++nf) {
        const size_t o = row * EMBED + col0 + nf * 16 + lr;
        store_stream(&out[o], base[o] + acc[m][nf][r]);
      }
    }
}

extern "C" void kernel_launch(void* const* d_in, const int* in_sizes, int n_in,
                              void* d_out, int out_size, void* d_ws, size_t ws_size,
                              hipStream_t stream) {
  const float* base = (const float*)d_in[0];
  const float* src  = (const float*)d_in[1];
  const int*   sub  = (const int*)d_in[2];
  const float* W    = (const float*)d_in[3];
  float* out = (float*)d_out;

  short* Wp  = (short*)d_ws;                       // 1 MB
  short* Wtp = Wp  + EMBED * KSEL;                 // 1 MB
  short* Tp  = Wtp + EMBED * KSEL;                 // 2 MB

  pack_w_kernel<<<EMBED * KSEL / 256, 256, 0, stream>>>(W, sub, Wp, Wtp);
  gemm1_kernel<<<BATCH / 16, 256, 0, stream>>>(base, src, Wp, Tp);
  gemm2_kernel<<<(BATCH / 64) * 16, 256, 0, stream>>>(base, Tp, Wtp, out);
}

// Round 16
// 123.499 us; speedup vs baseline: 1.3351x; 1.3351x over previous
//
#include <hip/hip_runtime.h>
#include <hip/hip_bf16.h>

typedef __attribute__((ext_vector_type(4))) float  f32x4;
typedef __attribute__((ext_vector_type(8))) short  short8;
typedef unsigned int u32;

#define EMBED 4096
#define LR    512
#define KSEL  128
#define BATCH 8192

__device__ __forceinline__ short f2bf(float x) {
  union { float f; unsigned u; } c; c.f = x;
  unsigned r = c.u + 0x7FFFu + ((c.u >> 16) & 1u);  // RNE
  return (short)(r >> 16);
}
__device__ __forceinline__ void gload16(const void* g, void* l) {
  __builtin_amdgcn_global_load_lds((const __attribute__((address_space(1))) u32*)g,
                                   (__attribute__((address_space(3))) u32*)l, 16, 0, 0);
}

// K0: gather selected columns of W, emit two bf16 MFMA-packed layouts.
// Wp : [e/8][128 cols][8]  (B-operand for GEMM1: kk-dim = embed)
// Wtp: [c/8][4096 e ][8]  (B-operand for GEMM2: kk-dim = sel index)
__global__ __launch_bounds__(256) void pack_w_kernel(
    const float* __restrict__ W, const int* __restrict__ sel,
    short* __restrict__ Wp, short* __restrict__ Wtp) {
  int idx = blockIdx.x * 256 + threadIdx.x;
  int e = idx >> 7;
  int c = idx & 127;
  int r = sel[c];
  short v = f2bf(W[e * LR + r]);
  Wp [(((e >> 3) << 7) + c) * 8 + (e & 7)] = v;
  Wtp[(((c >> 3) << 12) + e) * 8 + (c & 7)] = v;
}

// K1: Tp (packed bf16 [kk/8][8192][8]) = (src - base) @ Wsel
// R12 champion structure. Steady-state cost model: 138 MB HBM refetch
// (inputs evicted by the out-write allocating in the memory-side L3)
// at the machine's ~1.4 TB/s demand-miss ceiling = ~98 us. All pipes
// idle by design — this kernel sits on the miss-path wall.
__global__ __launch_bounds__(256, 2) void gemm1_kernel(
    const float* __restrict__ base, const float* __restrict__ src,
    const short* __restrict__ Wp, short* __restrict__ Tp) {
  __shared__ __align__(16) char smem[65536];   // 2 bufs x (16 rows x 1KB x 2 arr)
  const int t  = threadIdx.x;
  const int w  = t >> 6, l = t & 63;
  const int lr = l & 15, lg = l >> 4;
  const int row0 = blockIdx.x * 16;
  const int srow = t >> 6;       // base row (0..3), +4 per issue
  const int sc   = t & 63;       // 16B chunk within a 1KB row-slice

  #define STAGE(s, b) do {                                                  \
    char* d_ = smem + (b) * 32768 + t * 16;                                 \
    _Pragma("unroll")                                                       \
    for (int i = 0; i < 4; ++i) {                                           \
      const int row = i * 4 + srow;                                         \
      const size_t go = (size_t)(row0 + row) * EMBED + (s) * 256            \
                        + ((sc ^ (row & 7)) << 2);                          \
      gload16(base + go, d_ + i * 4096);                                    \
      gload16(src  + go, d_ + 16384 + i * 4096);                            \
    }                                                                       \
  } while (0)

  const short8* wq = (const short8*)Wp;
  f32x4 acc0 = {0.f, 0.f, 0.f, 0.f}, acc1 = {0.f, 0.f, 0.f, 0.f};

  STAGE(0, 0);
  int b = 0;
  for (int s = 0; s < 16; ++s) {
    __syncthreads();                         // buf b staged
    const int kc = s * 256;
    short8 bf[16];                           // B-frags first (older in queue)
    #pragma unroll
    for (int kstep = 0; kstep < 8; ++kstep) {
      const int kg = ((kc + kstep * 32) >> 3) + lg;
      bf[kstep * 2]     = wq[(size_t)kg * 128 + w * 32 + lr];
      bf[kstep * 2 + 1] = wq[(size_t)kg * 128 + w * 32 + 16 + lr];
    }
    if (s < 15) STAGE(s + 1, b ^ 1);         // flies under this step's compute
    const char* tb = smem + b * 32768 + lr * 1024;
    #pragma unroll
    for (int kstep = 0; kstep < 8; ++kstep) {
      const int j0 = (kstep * 8 + lg * 2)     ^ (lr & 7);
      const int j1 = (kstep * 8 + lg * 2 + 1) ^ (lr & 7);
      f32x4 b0 = *(const f32x4*)(tb + j0 * 16);
      f32x4 b1 = *(const f32x4*)(tb + j1 * 16);
      f32x4 s0 = *(const f32x4*)(tb + 16384 + j0 * 16);
      f32x4 s1 = *(const f32x4*)(tb + 16384 + j1 * 16);
      union { short8 v; __hip_bfloat162 h[4]; } u;
      u.h[0] = __float22bfloat162_rn(make_float2(s0[0] - b0[0], s0[1] - b0[1]));
      u.h[1] = __float22bfloat162_rn(make_float2(s0[2] - b0[2], s0[3] - b0[3]));
      u.h[2] = __float22bfloat162_rn(make_float2(s1[0] - b1[0], s1[1] - b1[1]));
      u.h[3] = __float22bfloat162_rn(make_float2(s1[2] - b1[2], s1[3] - b1[3]));
      acc0 = __builtin_amdgcn_mfma_f32_16x16x32_bf16(u.v, bf[kstep * 2],     acc0, 0, 0, 0);
      acc1 = __builtin_amdgcn_mfma_f32_16x16x32_bf16(u.v, bf[kstep * 2 + 1], acc1, 0, 0, 0);
    }
    b ^= 1;
  }
  #undef STAGE

  // lane holds T[row0 + 4lg + r][kk = w*32 + ct*16 + lr]
  #pragma unroll
  for (int ct = 0; ct < 2; ++ct) {
    f32x4 a = ct ? acc1 : acc0;
    const int kk = w * 32 + ct * 16 + lr;
    short* dst = Tp + (size_t)(((kk >> 3) << 13) + row0 + (lg << 2)) * 8 + (kk & 7);
    #pragma unroll
    for (int r = 0; r < 4; ++r) dst[r * 8] = f2bf(a[r]);
  }
}

// K2: out = base + T @ Wsel^T. Block: 64 rows x 256 cols, 4 waves.
// (R12 champion form: plain nontemporal stores — nt only, NOT sc1.)
__global__ __launch_bounds__(256) void gemm2_kernel(
    const float* __restrict__ base, const short* __restrict__ Tp,
    const short* __restrict__ Wtp, float* __restrict__ out) {
  const int t  = threadIdx.x;
  const int w  = t >> 6, l = t & 63;
  const int lr = l & 15, lg = l >> 4;
  const int mt = blockIdx.x >> 4, nt = blockIdx.x & 15;
  const int row0 = mt * 64;
  const int col0 = nt * 256 + w * 64;

  short8 afr[4][4];
  #pragma unroll
  for (int m = 0; m < 4; ++m)
    #pragma unroll
    for (int ks = 0; ks < 4; ++ks)
      afr[m][ks] = *(const short8*)(Tp + (size_t)(((ks * 4 + lg) << 13) + row0 + m * 16 + lr) * 8);

  f32x4 acc[4][4];
  #pragma unroll
  for (int m = 0; m < 4; ++m)
    #pragma unroll
    for (int nf = 0; nf < 4; ++nf) acc[m][nf] = (f32x4){0.f, 0.f, 0.f, 0.f};

  #pragma unroll
  for (int nf = 0; nf < 4; ++nf) {
    short8 bfr[4];
    #pragma unroll
    for (int ks = 0; ks < 4; ++ks)
      bfr[ks] = *(const short8*)(Wtp + (size_t)(((ks * 4 + lg) << 12) + col0 + nf * 16 + lr) * 8);
    #pragma unroll
    for (int m = 0; m < 4; ++m)
      #pragma unroll
      for (int ks = 0; ks < 4; ++ks)
        acc[m][nf] = __builtin_amdgcn_mfma_f32_16x16x32_bf16(afr[m][ks], bfr[ks], acc[m][nf], 0, 0, 0);
  }

  #pragma unroll
  for (int m = 0; m < 4; ++m)
    #pragma unroll
    for (int r = 0; r < 4; ++r) {
      const size_t row = row0 + m * 16 + lg * 4 + r;
      #pragma unroll
      for (int nf = 0; nf < 4; ++nf) {
        const size_t o = row * EMBED + col0 + nf * 16 + lr;
        float v = base[o] + acc[m][nf][r];
        __builtin_nontemporal_store(v, &out[o]);
      }
    }
}

extern "C" void kernel_launch(void* const* d_in, const int* in_sizes, int n_in,
                              void* d_out, int out_size, void* d_ws, size_t ws_size,
                              hipStream_t stream) {
  const float* base = (const float*)d_in[0];
  const float* src  = (const float*)d_in[1];
  const int*   sub  = (const int*)d_in[2];
  const float* W    = (const float*)d_in[3];
  float* out = (float*)d_out;

  short* Wp  = (short*)d_ws;                       // 1 MB
  short* Wtp = Wp  + EMBED * KSEL;                 // 1 MB
  short* Tp  = Wtp + EMBED * KSEL;                 // 2 MB

  pack_w_kernel<<<EMBED * KSEL / 256, 256, 0, stream>>>(W, sub, Wp, Wtp);
  gemm1_kernel<<<BATCH / 16, 256, 0, stream>>>(base, src, Wp, Tp);
  gemm2_kernel<<<(BATCH / 64) * 16, 256, 0, stream>>>(base, Tp, Wtp, out);
}